// Round 12
// baseline (132.729 us; speedup 1.0000x reference)
//
#include <hip/hip_runtime.h>

#define T_TOK 512
#define HID   2048
#define NEXP  16
#define IDIM  1024
#define KC    64
#define WSTRIDE 2048   // row stride (fp32 elems) of both w13 ([H][2I]) and w2 ([I][H])

typedef __attribute__((ext_vector_type(8)))  short bf16x8;
typedef __attribute__((ext_vector_type(16))) float f32x16;
typedef __attribute__((ext_vector_type(4)))  float float4v;

__device__ __forceinline__ unsigned short f2bf(float f) {
    union { float f; unsigned u; } v; v.f = f;
    return (unsigned short)((v.u + 0x7FFFu + ((v.u >> 16) & 1u)) >> 16);
}

__device__ __forceinline__ bf16x8 pack8(const float* s) {
    bf16x8 r;
#pragma unroll
    for (int i = 0; i < 8; ++i) r[i] = (short)f2bf(s[i]);
    return r;
}

// LDS-only barrier: waits ds ops, NOT the global-load queue (no vmcnt drain).
#define LGKM_BAR() { asm volatile("s_waitcnt lgkmcnt(0)" ::: "memory"); \
    __builtin_amdgcn_s_barrier(); __builtin_amdgcn_sched_barrier(0); }

// ---------------- router (+ x -> bf16 conversion) ----------------
__global__ __launch_bounds__(256) void router_kernel(
    const float* __restrict__ x, const float* __restrict__ rw,
    int* __restrict__ cnt, int* __restrict__ tok,
    int* __restrict__ rowid, float* __restrict__ wt,
    unsigned short* __restrict__ xb)
{
    int t = blockIdx.x;
    int tid = threadIdx.x;
    const float* xr = x + (size_t)t * HID;

    {
        int c = tid * 8;
        float4v a = *(const float4v*)(xr + c);
        float4v b = *(const float4v*)(xr + c + 4);
        float tmp[8];
#pragma unroll
        for (int i = 0; i < 4; ++i) { tmp[i] = a[i]; tmp[4 + i] = b[i]; }
        *(bf16x8*)(xb + (size_t)t * HID + c) = pack8(tmp);
    }

    float acc[NEXP];
#pragma unroll
    for (int e = 0; e < NEXP; ++e) acc[e] = 0.f;

    for (int k = tid; k < HID; k += 256) {
        float xv = xr[k];
#pragma unroll
        for (int e = 0; e < NEXP; ++e) acc[e] += xv * rw[e * HID + k];
    }

    __shared__ float red[4][NEXP];
    int lane = tid & 63, wv = tid >> 6;
#pragma unroll
    for (int e = 0; e < NEXP; ++e) {
        float v = acc[e];
#pragma unroll
        for (int off = 32; off > 0; off >>= 1) v += __shfl_down(v, off);
        if (lane == 0) red[wv][e] = v;
    }
    __syncthreads();

    if (tid == 0) {
        float l[NEXP];
        float mx = -1e30f;
#pragma unroll
        for (int e = 0; e < NEXP; ++e) {
            l[e] = red[0][e] + red[1][e] + red[2][e] + red[3][e];
            mx = fmaxf(mx, l[e]);
        }
        float s = 0.f;
#pragma unroll
        for (int e = 0; e < NEXP; ++e) { l[e] = __expf(l[e] - mx); s += l[e]; }
        float inv_s = 1.f / s;
        int i0 = 0; float v0 = -1.f;
        int i1 = 0; float v1 = -2.f;
#pragma unroll
        for (int e = 0; e < NEXP; ++e) {
            float p = l[e] * inv_s;
            if (p > v0)      { v1 = v0; i1 = i0; v0 = p; i0 = e; }
            else if (p > v1) { v1 = p; i1 = e; }
        }
        float inv = 1.f / (v0 + v1);
        int p0 = atomicAdd(&cnt[i0], 1);
        tok[i0 * T_TOK + p0] = t; rowid[i0 * T_TOK + p0] = 2 * t;     wt[i0 * T_TOK + p0] = v0 * inv;
        int p1 = atomicAdd(&cnt[i1], 1);
        tok[i1 * T_TOK + p1] = t; rowid[i1 * T_TOK + p1] = 2 * t + 1; wt[i1 * T_TOK + p1] = v1 * inv;
    }
}

// ---- staging macros ----
// W role: wcol = tid&63 (1 col), kq = tid>>6 (8 k-rows). Coalesced 256B row reads,
// NON-TEMPORAL (streaming), register transpose, swizzled b128 store (0-conflict).
#define LOADW(r, kk_) { _Pragma("unroll") for (int j = 0; j < 8; ++j) \
    r[j] = __builtin_nontemporal_load(&wsrc[(size_t)((kk_) + kq * 8 + j) * WSTRIDE]); }

#define STOREW(r, bufi) { \
    *(bf16x8*)((char*)Ws[bufi] + ((wcol * 128 + kq * 16) ^ ((wcol & 7) << 4))) = pack8(r); }

// X/H role: xrow = tid>>2 (row), xq = tid&3 (32B quarter of the 128B bf16 row)
#define LOADX(r, kk_) { \
    r[0] = *(const bf16x8*)(xsrc + (kk_)); \
    r[1] = *(const bf16x8*)(xsrc + (kk_) + 8); }

#define STOREX(r, bufi) { \
    *(bf16x8*)((char*)Xs[bufi] + ((xrow * 128 + xq * 32)      ^ xswz)) = r[0]; \
    *(bf16x8*)((char*)Xs[bufi] + ((xrow * 128 + xq * 32 + 16) ^ xswz)) = r[1]; }

// ---------------- gemm1: h = wt * silu(x@Wg) * (x@Wu), 32x32x16 MFMA ----------------
// 512 blocks (XCD-swizzled): e = bid>>5, hcol-tile = (bid&31)*32. M=128 tokens.
// 4-deep W register pipeline: store of batch j+1 at half-phase j waits loads
// issued at half-phase j-3 (~3 hp >= HBM latency). X (L2-resident) stays 2-deep.
__global__ __launch_bounds__(512, 4) void gemm1_kernel(
    const unsigned short* __restrict__ xb, const float* __restrict__ w13,
    const int* __restrict__ cnt, const int* __restrict__ tok,
    const int* __restrict__ rowid, const float* __restrict__ wt,
    unsigned short* __restrict__ h)
{
    int b0 = blockIdx.x;
    int bid = (b0 & 7) * 64 + (b0 >> 3);   // XCD swizzle
    int e   = bid >> 5;
    int c0h = (bid & 31) * 32;
    int n = cnt[e];
    int tid = threadIdx.x;

    __shared__ __align__(16) short Xs[2][128 * KC];   // [token][k], 16 KB each
    __shared__ __align__(16) short Ws[2][64 * KC];    // [wcol][k]: 0-31 gate, 32-63 up
    __shared__ float Ex[4][16][64];                    // u-exchange, 16 KB
    __shared__ int   tks[128];
    __shared__ int   rws[128];
    __shared__ float wts[128];

    const float* wbase = w13 + (size_t)e * HID * (2 * IDIM);

    int wcol = tid & 63, kq = tid >> 6;
    const float* wsrc = wbase + ((wcol < 32) ? (c0h + wcol)
                                             : (IDIM + c0h + (wcol - 32)));
    int xrow = tid >> 2, xq = tid & 3;
    int xswz = (xrow & 7) << 4;

    int wave = tid >> 6, lane = tid & 63;
    int wm = wave & 3, wn = wave >> 2;       // M-strip, {0:gate, 1:up}
    int lrow = lane & 31, lhalf = lane >> 5;
    int swz = (lrow & 7) << 4;

#define G1_MFMA(bufi) { if (wm * 32 < nt) { _Pragma("unroll") \
    for (int s = 0; s < 4; ++s) { \
        int kb = s * 32 + lhalf * 16; \
        bf16x8 a = *(const bf16x8*)((char*)Xs[bufi] + (((wm * 32 + lrow) * 128 + kb) ^ swz)); \
        bf16x8 b = *(const bf16x8*)((char*)Ws[bufi] + (((wn * 32 + lrow) * 128 + kb) ^ swz)); \
        acc = __builtin_amdgcn_mfma_f32_32x32x16_bf16(a, b, acc, 0, 0, 0); \
    } } }

    for (int t0 = 0; t0 < n; t0 += 128) {
        int nt = min(128, n - t0);
        __syncthreads();
        if (tid < 128) {
            int idx = t0 + min(tid, nt - 1);
            tks[tid] = tok[e * T_TOK + idx];
            rws[tid] = rowid[e * T_TOK + idx];
            wts[tid] = wt[e * T_TOK + idx];
        }
        __syncthreads();

        const unsigned short* xsrc = xb + (size_t)tks[xrow] * HID + xq * 16;

        f32x16 acc = (f32x16)0.f;
        float  rWa[8], rWb[8], rWc[8], rWd[8];
        bf16x8 rXa[2], rXb[2];

        // prologue: X first (cheap waits), then 4 W batches; store batch 0
        LOADX(rXa, 0); LOADX(rXb, KC);
        LOADW(rWa, 0); LOADW(rWb, KC); LOADW(rWc, 2 * KC); LOADW(rWd, 3 * KC);
        STOREW(rWa, 0); STOREX(rXa, 0);
        LGKM_BAR();

        // main: groups of 4 half-phases (batch j consumed at hp j from LDS[j&1])
        for (int i = 0; i < HID / KC - 4; i += 4) {
            LOADW(rWa, (i + 4) * KC); LOADX(rXa, (i + 2) * KC);
            G1_MFMA(0);
            STOREW(rWb, 1); STOREX(rXb, 1);
            LGKM_BAR();
            LOADW(rWb, (i + 5) * KC); LOADX(rXb, (i + 3) * KC);
            G1_MFMA(1);
            STOREW(rWc, 0); STOREX(rXa, 0);
            LGKM_BAR();
            LOADW(rWc, (i + 6) * KC); LOADX(rXa, (i + 4) * KC);
            G1_MFMA(0);
            STOREW(rWd, 1); STOREX(rXb, 1);
            LGKM_BAR();
            LOADW(rWd, (i + 7) * KC); LOADX(rXb, (i + 5) * KC);
            G1_MFMA(1);
            STOREW(rWa, 0); STOREX(rXa, 0);
            LGKM_BAR();
        }
        {   // tail: batches NB-4..NB-1 already in rWa..rWd, LDS0 = batch NB-4
            const int NB = HID / KC;
            LOADX(rXa, (NB - 2) * KC);
            G1_MFMA(0);
            STOREW(rWb, 1); STOREX(rXb, 1);
            LGKM_BAR();
            LOADX(rXb, (NB - 1) * KC);
            G1_MFMA(1);
            STOREW(rWc, 0); STOREX(rXa, 0);
            LGKM_BAR();
            G1_MFMA(0);
            STOREW(rWd, 1); STOREX(rXb, 1);
            LGKM_BAR();
            G1_MFMA(1);
        }

        // epilogue: u-waves -> LDS; g-waves compute silu(g)*u*wt -> h (bf16)
        if (wn == 1) {
#pragma unroll
            for (int q = 0; q < 16; ++q) Ex[wm][q][lane] = acc[q];
        }
        __syncthreads();
        if (wn == 0) {
#pragma unroll
            for (int q = 0; q < 16; ++q) {
                int r = wm * 32 + (q & 3) + 8 * (q >> 2) + 4 * lhalf;
                if (r < nt) {
                    float g = acc[q];
                    float u = Ex[wm][q][lane];
                    float sg = g / (1.f + __expf(-g));
                    h[(size_t)rws[r] * IDIM + c0h + lrow] = f2bf(wts[r] * sg * u);
                }
            }
        }
    }
}

// ---------------- gemm2: out[t] += h[row] @ w2[e], 32x32x16 MFMA ----------------
// 512 blocks (XCD-swizzled): e = bid>>5, outcol-tile = (bid&31)*64. M=128 rows.
__global__ __launch_bounds__(512, 4) void gemm2_kernel(
    const unsigned short* __restrict__ h, const float* __restrict__ w2,
    const int* __restrict__ cnt, const int* __restrict__ tok,
    const int* __restrict__ rowid,
    float* __restrict__ out)
{
    int b0 = blockIdx.x;
    int bid = (b0 & 7) * 64 + (b0 >> 3);
    int e  = bid >> 5;
    int c0 = (bid & 31) * 64;
    int n = cnt[e];
    int tid = threadIdx.x;

    __shared__ __align__(16) short Xs[2][128 * KC];   // h rows
    __shared__ __align__(16) short Ws[2][64 * KC];    // w2 cols
    __shared__ int   tks[128];
    __shared__ int   rws[128];

    const float* wbase = w2 + (size_t)e * IDIM * HID;

    int wcol = tid & 63, kq = tid >> 6;
    const float* wsrc = wbase + c0 + wcol;
    int xrow = tid >> 2, xq = tid & 3;
    int xswz = (xrow & 7) << 4;

    int wave = tid >> 6, lane = tid & 63;
    int wm = wave & 3, wn = wave >> 2;
    int lrow = lane & 31, lhalf = lane >> 5;
    int swz = (lrow & 7) << 4;

#define G2_MFMA(bufi) { if (wm * 32 < nt) { _Pragma("unroll") \
    for (int s = 0; s < 4; ++s) { \
        int kb = s * 32 + lhalf * 16; \
        bf16x8 a = *(const bf16x8*)((char*)Xs[bufi] + (((wm * 32 + lrow) * 128 + kb) ^ swz)); \
        bf16x8 b = *(const bf16x8*)((char*)Ws[bufi] + (((wn * 32 + lrow) * 128 + kb) ^ swz)); \
        acc = __builtin_amdgcn_mfma_f32_32x32x16_bf16(a, b, acc, 0, 0, 0); \
    } } }

    for (int t0 = 0; t0 < n; t0 += 128) {
        int nt = min(128, n - t0);
        __syncthreads();
        if (tid < 128) {
            int idx = t0 + min(tid, nt - 1);
            tks[tid] = tok[e * T_TOK + idx];
            rws[tid] = rowid[e * T_TOK + idx];
        }
        __syncthreads();

        const unsigned short* xsrc = h + (size_t)rws[xrow] * IDIM + xq * 16;

        f32x16 acc = (f32x16)0.f;
        float  rWa[8], rWb[8], rWc[8], rWd[8];
        bf16x8 rXa[2], rXb[2];

        LOADX(rXa, 0); LOADX(rXb, KC);
        LOADW(rWa, 0); LOADW(rWb, KC); LOADW(rWc, 2 * KC); LOADW(rWd, 3 * KC);
        STOREW(rWa, 0); STOREX(rXa, 0);
        LGKM_BAR();

        for (int i = 0; i < IDIM / KC - 4; i += 4) {
            LOADW(rWa, (i + 4) * KC); LOADX(rXa, (i + 2) * KC);
            G2_MFMA(0);
            STOREW(rWb, 1); STOREX(rXb, 1);
            LGKM_BAR();
            LOADW(rWb, (i + 5) * KC); LOADX(rXb, (i + 3) * KC);
            G2_MFMA(1);
            STOREW(rWc, 0); STOREX(rXa, 0);
            LGKM_BAR();
            LOADW(rWc, (i + 6) * KC); LOADX(rXa, (i + 4) * KC);
            G2_MFMA(0);
            STOREW(rWd, 1); STOREX(rXb, 1);
            LGKM_BAR();
            LOADW(rWd, (i + 7) * KC); LOADX(rXb, (i + 5) * KC);
            G2_MFMA(1);
            STOREW(rWa, 0); STOREX(rXa, 0);
            LGKM_BAR();
        }
        {
            const int NB = IDIM / KC;
            LOADX(rXa, (NB - 2) * KC);
            G2_MFMA(0);
            STOREW(rWb, 1); STOREX(rXb, 1);
            LGKM_BAR();
            LOADX(rXb, (NB - 1) * KC);
            G2_MFMA(1);
            STOREW(rWc, 0); STOREX(rXa, 0);
            LGKM_BAR();
            G2_MFMA(0);
            STOREW(rWd, 1); STOREX(rXb, 1);
            LGKM_BAR();
            G2_MFMA(1);
        }

#pragma unroll
        for (int q = 0; q < 16; ++q) {
            int r = wm * 32 + (q & 3) + 8 * (q >> 2) + 4 * lhalf;
            if (r < nt)
                atomicAdd(&out[(size_t)tks[r] * HID + c0 + wn * 32 + lrow], acc[q]);
        }
    }
}

extern "C" void kernel_launch(void* const* d_in, const int* in_sizes, int n_in,
                              void* d_out, int out_size, void* d_ws, size_t ws_size,
                              hipStream_t stream) {
    const float* x   = (const float*)d_in[0];   // [T, H]
    const float* rw  = (const float*)d_in[1];   // [E, H]
    const float* w13 = (const float*)d_in[2];   // [E, H, 2I]
    const float* w2  = (const float*)d_in[3];   // [E, I, H]
    float* out = (float*)d_out;                 // [T, H]

    char* ws = (char*)d_ws;
    int*   cnt   = (int*)ws;
    int*   tok   = (int*)(ws + 1024);
    int*   rowid = (int*)(ws + 1024 + 32768);
    float* wt    = (float*)(ws + 1024 + 65536);
    unsigned short* h  = (unsigned short*)(ws + 131072);            // [2T, I] bf16
    unsigned short* xb = (unsigned short*)(ws + 131072 + 2097152);  // [T, H] bf16

    hipMemsetAsync(out, 0, (size_t)T_TOK * HID * sizeof(float), stream);
    hipMemsetAsync(cnt, 0, 1024, stream);

    router_kernel<<<T_TOK, 256, 0, stream>>>(x, rw, cnt, tok, rowid, wt, xb);
    gemm1_kernel<<<512, 512, 0, stream>>>(xb, w13, cnt, tok, rowid, wt, h);
    gemm2_kernel<<<512, 512, 0, stream>>>(h, w2, cnt, tok, rowid, out);
}

// Round 13
// 120.267 us; speedup vs baseline: 1.1036x; 1.1036x over previous
//
#include <hip/hip_runtime.h>

#define T_TOK 512
#define HID   2048
#define NEXP  16
#define IDIM  1024
#define KC    64
#define WSTRIDE 2048   // row stride (fp32 elems) of both w13 ([H][2I]) and w2 ([I][H])

typedef __attribute__((ext_vector_type(8)))  short bf16x8;
typedef __attribute__((ext_vector_type(16))) float f32x16;
typedef __attribute__((ext_vector_type(4)))  float float4v;

__device__ __forceinline__ unsigned short f2bf(float f) {
    union { float f; unsigned u; } v; v.f = f;
    return (unsigned short)((v.u + 0x7FFFu + ((v.u >> 16) & 1u)) >> 16);
}

__device__ __forceinline__ bf16x8 pack8(const float* s) {
    bf16x8 r;
#pragma unroll
    for (int i = 0; i < 8; ++i) r[i] = (short)f2bf(s[i]);
    return r;
}

// LDS-only barrier: waits ds ops, NOT the global-load queue (no vmcnt drain).
#define LGKM_BAR() { asm volatile("s_waitcnt lgkmcnt(0)" ::: "memory"); \
    __builtin_amdgcn_s_barrier(); __builtin_amdgcn_sched_barrier(0); }

// ---------------- router (+ x -> bf16 conversion), single x pass ----------------
__global__ __launch_bounds__(256) void router_kernel(
    const float* __restrict__ x, const float* __restrict__ rw,
    int* __restrict__ cnt, int* __restrict__ tok,
    int* __restrict__ rowid, float* __restrict__ wt,
    unsigned short* __restrict__ xb)
{
    int t = blockIdx.x;
    int tid = threadIdx.x;
    const float* xr = x + (size_t)t * HID;

    // single pass: load 8 elems, convert to bf16, and accumulate router dots
    float acc[NEXP];
#pragma unroll
    for (int e = 0; e < NEXP; ++e) acc[e] = 0.f;
    {
        int c = tid * 8;
        float4v a = *(const float4v*)(xr + c);
        float4v b = *(const float4v*)(xr + c + 4);
        float tmp[8];
#pragma unroll
        for (int i = 0; i < 4; ++i) { tmp[i] = a[i]; tmp[4 + i] = b[i]; }
        *(bf16x8*)(xb + (size_t)t * HID + c) = pack8(tmp);
#pragma unroll
        for (int j = 0; j < 8; ++j) {
            float xv = tmp[j];
#pragma unroll
            for (int e = 0; e < NEXP; ++e) acc[e] += xv * rw[e * HID + c + j];
        }
    }

    __shared__ float red[4][NEXP];
    int lane = tid & 63, wv = tid >> 6;
#pragma unroll
    for (int e = 0; e < NEXP; ++e) {
        float v = acc[e];
#pragma unroll
        for (int off = 32; off > 0; off >>= 1) v += __shfl_down(v, off);
        if (lane == 0) red[wv][e] = v;
    }
    __syncthreads();

    if (tid == 0) {
        float l[NEXP];
        float mx = -1e30f;
#pragma unroll
        for (int e = 0; e < NEXP; ++e) {
            l[e] = red[0][e] + red[1][e] + red[2][e] + red[3][e];
            mx = fmaxf(mx, l[e]);
        }
        float s = 0.f;
#pragma unroll
        for (int e = 0; e < NEXP; ++e) { l[e] = __expf(l[e] - mx); s += l[e]; }
        float inv_s = 1.f / s;
        int i0 = 0; float v0 = -1.f;
        int i1 = 0; float v1 = -2.f;
#pragma unroll
        for (int e = 0; e < NEXP; ++e) {
            float p = l[e] * inv_s;
            if (p > v0)      { v1 = v0; i1 = i0; v0 = p; i0 = e; }
            else if (p > v1) { v1 = p; i1 = e; }
        }
        float inv = 1.f / (v0 + v1);
        int p0 = atomicAdd(&cnt[i0], 1);
        tok[i0 * T_TOK + p0] = t; rowid[i0 * T_TOK + p0] = 2 * t;     wt[i0 * T_TOK + p0] = v0 * inv;
        int p1 = atomicAdd(&cnt[i1], 1);
        tok[i1 * T_TOK + p1] = t; rowid[i1 * T_TOK + p1] = 2 * t + 1; wt[i1 * T_TOK + p1] = v1 * inv;
    }
}

// ---- staging macros ----
// W role: wcol = tid&63 (1 col), kq = tid>>6 (8 k-rows). Coalesced 256B row reads,
// NON-TEMPORAL (streaming), register transpose, swizzled b128 store (0-conflict).
#define LOADW(r, kk_) { _Pragma("unroll") for (int j = 0; j < 8; ++j) \
    r[j] = __builtin_nontemporal_load(&wsrc[(size_t)((kk_) + kq * 8 + j) * WSTRIDE]); }

#define STOREW(r, bufi) { \
    *(bf16x8*)((char*)Ws[bufi] + ((wcol * 128 + kq * 16) ^ ((wcol & 7) << 4))) = pack8(r); }

// X/H role: xrow = tid>>2 (row), xq = tid&3 (32B quarter of the 128B bf16 row)
#define LOADX(r, kk_) { \
    r[0] = *(const bf16x8*)(xsrc + (kk_)); \
    r[1] = *(const bf16x8*)(xsrc + (kk_) + 8); }

#define STOREX(r, bufi) { \
    *(bf16x8*)((char*)Xs[bufi] + ((xrow * 128 + xq * 32)      ^ xswz)) = r[0]; \
    *(bf16x8*)((char*)Xs[bufi] + ((xrow * 128 + xq * 32 + 16) ^ xswz)) = r[1]; }

// ---------------- gemm1: h = wt * silu(x@Wg) * (x@Wu), 32x32x16 MFMA ----------------
// 512 blocks (XCD-swizzled): e = bid>>5, hcol-tile = (bid&31)*32. M=128 tokens.
// W-tile = 64 wcols (32 gate + 32 up). 8 waves = 4 M-strips x {gate, up}.
__global__ __launch_bounds__(512, 4) void gemm1_kernel(
    const unsigned short* __restrict__ xb, const float* __restrict__ w13,
    const int* __restrict__ cnt, const int* __restrict__ tok,
    const int* __restrict__ rowid, const float* __restrict__ wt,
    unsigned short* __restrict__ h)
{
    int b0 = blockIdx.x;
    int bid = (b0 & 7) * 64 + (b0 >> 3);   // XCD swizzle: same-expert blocks share an XCD
    int e   = bid >> 5;
    int c0h = (bid & 31) * 32;
    int n = cnt[e];
    int tid = threadIdx.x;

    __shared__ __align__(16) short Xs[2][128 * KC];   // [token][k], 16 KB each
    __shared__ __align__(16) short Ws[2][64 * KC];    // [wcol][k]: 0-31 gate, 32-63 up; 8 KB each
    __shared__ float Ex[4][16][64];                    // u-exchange, 16 KB
    __shared__ int   tks[128];
    __shared__ int   rws[128];
    __shared__ float wts[128];

    const float* wbase = w13 + (size_t)e * HID * (2 * IDIM);

    int wcol = tid & 63, kq = tid >> 6;
    const float* wsrc = wbase + ((wcol < 32) ? (c0h + wcol)
                                             : (IDIM + c0h + (wcol - 32)));
    int xrow = tid >> 2, xq = tid & 3;
    int xswz = (xrow & 7) << 4;

    int wave = tid >> 6, lane = tid & 63;
    int wm = wave & 3, wn = wave >> 2;       // M-strip, {0:gate, 1:up}
    int lrow = lane & 31, lhalf = lane >> 5;
    int swz = (lrow & 7) << 4;

#define G1_MFMA(bufi) { if (wm * 32 < nt) { _Pragma("unroll") \
    for (int s = 0; s < 4; ++s) { \
        int kb = s * 32 + lhalf * 16; \
        bf16x8 a = *(const bf16x8*)((char*)Xs[bufi] + (((wm * 32 + lrow) * 128 + kb) ^ swz)); \
        bf16x8 b = *(const bf16x8*)((char*)Ws[bufi] + (((wn * 32 + lrow) * 128 + kb) ^ swz)); \
        acc = __builtin_amdgcn_mfma_f32_32x32x16_bf16(a, b, acc, 0, 0, 0); \
    } } }

    for (int t0 = 0; t0 < n; t0 += 128) {
        int nt = min(128, n - t0);
        __syncthreads();
        if (tid < 128) {
            int idx = t0 + min(tid, nt - 1);
            tks[tid] = tok[e * T_TOK + idx];
            rws[tid] = rowid[e * T_TOK + idx];
            wts[tid] = wt[e * T_TOK + idx];
        }
        __syncthreads();

        const unsigned short* xsrc = xb + (size_t)tks[xrow] * HID + xq * 16;

        f32x16 acc = (f32x16)0.f;
        float  rWa[8], rWb[8];
        bf16x8 rXa[2], rXb[2];

        LOADW(rWa, 0);  LOADX(rXa, 0);
        LOADW(rWb, KC); LOADX(rXb, KC);
        STOREW(rWa, 0); STOREX(rXa, 0);     // vmcnt counted: rWb batch stays in flight
        LGKM_BAR();

        for (int p = 0; p < HID / KC; p += 2) {
            int kf0 = (p + 2) * KC, kf1 = (p + 3) * KC;
            if (kf0 < HID) { LOADW(rWa, kf0); LOADX(rXa, kf0); }  // issue k+2
            G1_MFMA(0);
            STOREW(rWb, 1); STOREX(rXb, 1);   // waits rWb only (counted), k+2 in flight
            LGKM_BAR();
            if (kf1 < HID) { LOADW(rWb, kf1); LOADX(rXb, kf1); }  // issue k+3
            G1_MFMA(1);
            if (kf0 < HID) { STOREW(rWa, 0); STOREX(rXa, 0); }
            LGKM_BAR();
        }

        // epilogue: u-waves -> LDS; g-waves compute silu(g)*u*wt -> h (bf16)
        if (wn == 1) {
#pragma unroll
            for (int q = 0; q < 16; ++q) Ex[wm][q][lane] = acc[q];
        }
        __syncthreads();
        if (wn == 0) {
#pragma unroll
            for (int q = 0; q < 16; ++q) {
                int r = wm * 32 + (q & 3) + 8 * (q >> 2) + 4 * lhalf;
                if (r < nt) {
                    float g = acc[q];
                    float u = Ex[wm][q][lane];
                    float sg = g / (1.f + __expf(-g));
                    h[(size_t)rws[r] * IDIM + c0h + lrow] = f2bf(wts[r] * sg * u);
                }
            }
        }
    }
}

// ---------------- gemm2: out[t] += h[row] @ w2[e], 32x32x16 MFMA ----------------
// 512 blocks (XCD-swizzled): e = bid>>5, outcol-tile = (bid&31)*64. M=128 rows.
__global__ __launch_bounds__(512, 4) void gemm2_kernel(
    const unsigned short* __restrict__ h, const float* __restrict__ w2,
    const int* __restrict__ cnt, const int* __restrict__ tok,
    const int* __restrict__ rowid,
    float* __restrict__ out)
{
    int b0 = blockIdx.x;
    int bid = (b0 & 7) * 64 + (b0 >> 3);
    int e  = bid >> 5;
    int c0 = (bid & 31) * 64;
    int n = cnt[e];
    int tid = threadIdx.x;

    __shared__ __align__(16) short Xs[2][128 * KC];   // h rows
    __shared__ __align__(16) short Ws[2][64 * KC];    // w2 cols
    __shared__ int   tks[128];
    __shared__ int   rws[128];

    const float* wbase = w2 + (size_t)e * IDIM * HID;

    int wcol = tid & 63, kq = tid >> 6;
    const float* wsrc = wbase + c0 + wcol;
    int xrow = tid >> 2, xq = tid & 3;
    int xswz = (xrow & 7) << 4;

    int wave = tid >> 6, lane = tid & 63;
    int wm = wave & 3, wn = wave >> 2;
    int lrow = lane & 31, lhalf = lane >> 5;
    int swz = (lrow & 7) << 4;

#define G2_MFMA(bufi) { if (wm * 32 < nt) { _Pragma("unroll") \
    for (int s = 0; s < 4; ++s) { \
        int kb = s * 32 + lhalf * 16; \
        bf16x8 a = *(const bf16x8*)((char*)Xs[bufi] + (((wm * 32 + lrow) * 128 + kb) ^ swz)); \
        bf16x8 b = *(const bf16x8*)((char*)Ws[bufi] + (((wn * 32 + lrow) * 128 + kb) ^ swz)); \
        acc = __builtin_amdgcn_mfma_f32_32x32x16_bf16(a, b, acc, 0, 0, 0); \
    } } }

    for (int t0 = 0; t0 < n; t0 += 128) {
        int nt = min(128, n - t0);
        __syncthreads();
        if (tid < 128) {
            int idx = t0 + min(tid, nt - 1);
            tks[tid] = tok[e * T_TOK + idx];
            rws[tid] = rowid[e * T_TOK + idx];
        }
        __syncthreads();

        const unsigned short* xsrc = h + (size_t)rws[xrow] * IDIM + xq * 16;

        f32x16 acc = (f32x16)0.f;
        float  rWa[8], rWb[8];
        bf16x8 rXa[2], rXb[2];

        LOADW(rWa, 0);  LOADX(rXa, 0);
        LOADW(rWb, KC); LOADX(rXb, KC);
        STOREW(rWa, 0); STOREX(rXa, 0);
        LGKM_BAR();

        for (int p = 0; p < IDIM / KC; p += 2) {
            int kf0 = (p + 2) * KC, kf1 = (p + 3) * KC;
            if (kf0 < IDIM) { LOADW(rWa, kf0); LOADX(rXa, kf0); }
            G2_MFMA(0);
            STOREW(rWb, 1); STOREX(rXb, 1);
            LGKM_BAR();
            if (kf1 < IDIM) { LOADW(rWb, kf1); LOADX(rXb, kf1); }
            G2_MFMA(1);
            if (kf0 < IDIM) { STOREW(rWa, 0); STOREX(rXa, 0); }
            LGKM_BAR();
        }

#pragma unroll
        for (int q = 0; q < 16; ++q) {
            int r = wm * 32 + (q & 3) + 8 * (q >> 2) + 4 * lhalf;
            if (r < nt)
                atomicAdd(&out[(size_t)tks[r] * HID + c0 + wn * 32 + lrow], acc[q]);
        }
    }
}

extern "C" void kernel_launch(void* const* d_in, const int* in_sizes, int n_in,
                              void* d_out, int out_size, void* d_ws, size_t ws_size,
                              hipStream_t stream) {
    const float* x   = (const float*)d_in[0];   // [T, H]
    const float* rw  = (const float*)d_in[1];   // [E, H]
    const float* w13 = (const float*)d_in[2];   // [E, H, 2I]
    const float* w2  = (const float*)d_in[3];   // [E, I, H]
    float* out = (float*)d_out;                 // [T, H]

    char* ws = (char*)d_ws;
    int*   cnt   = (int*)ws;
    int*   tok   = (int*)(ws + 1024);
    int*   rowid = (int*)(ws + 1024 + 32768);
    float* wt    = (float*)(ws + 1024 + 65536);
    unsigned short* h  = (unsigned short*)(ws + 131072);            // [2T, I] bf16
    unsigned short* xb = (unsigned short*)(ws + 131072 + 2097152);  // [T, H] bf16

    hipMemsetAsync(out, 0, (size_t)T_TOK * HID * sizeof(float), stream);
    hipMemsetAsync(cnt, 0, 1024, stream);

    router_kernel<<<T_TOK, 256, 0, stream>>>(x, rw, cnt, tok, rowid, wt, xb);
    gemm1_kernel<<<512, 512, 0, stream>>>(xb, w13, cnt, tok, rowid, wt, h);
    gemm2_kernel<<<512, 512, 0, stream>>>(h, w2, cnt, tok, rowid, out);
}